// Round 1
// 1096.041 us; speedup vs baseline: 1.3015x; 1.3015x over previous
//
#include <hip/hip_runtime.h>
#include <cstdint>
#include <cstddef>

// FraudDetector hetero-GAT on MI355X.
// R9: (a) dead-code elimination: output depends only on layer2-post <- layer1
//     {user,post}; entity path and layer2 user/ent removed (CSR now 4 rels,
//     1.45M edges, 300k nodes). (b) algebraic refactor: sum_e a_e*(H W)[src]
//     = (sum_e a_e*H[src]) @ W -- aggregate raw f32 H rows (shared across
//     relations, L3-resident) into per-dst/head sums G, then one dst-side
//     stacked GEMM [Nd x 512]@[512 x 128] (bf16x2-split, f32 G input; relu+
//     summed-bias fused). als = H @ (Wsrc asrc) precomputed vectors.
//     Agg inner loop: 4 edges in flight (clamped loads, weight-gated).
#define N_USER 100000
#define N_POST 50000
#define TEXT_D 768
#define USER_D 64
#define E_PUB 150000
#define E_REP 300000
#define E_INT 500000
#define E_FOL 500000
#define E_TOT 1450000   // pub+rep+int+fol
#define N_TOT 300000    // 50k+50k+100k+100k concatenated dst spaces

typedef unsigned short ushort_t;
typedef float f4v __attribute__((ext_vector_type(4)));
typedef short s8v __attribute__((ext_vector_type(8)));
typedef unsigned short u4v __attribute__((ext_vector_type(4)));

__device__ __forceinline__ float leaky(float v) { return v > 0.f ? v : 0.2f * v; }
__device__ __forceinline__ void split_bf(float x, ushort_t& hi, ushort_t& lo) {
  unsigned u = __float_as_uint(x);
  hi = (ushort_t)(u >> 16);
  float r = x - __uint_as_float(u & 0xFFFF0000u);
  lo = (ushort_t)(__float_as_uint(r) >> 16);
}

struct Ptrs4 { const int* p[4]; };

// ---------------------------------------------------------------------------
// wvec: wv[(lr*2+h)*128+k] = sum_c W[lr][k][h*128+c] * a[lr][h][c]
// (used for both dst-attn (Wdst,adst) and src-attn (Wsrc,asrc) vectors)
__global__ void wvec_kernel(const float* __restrict__ W, const float* __restrict__ av,
                            float* __restrict__ wv) {
  int b = blockIdx.x;              // 20 = lr(10) * h(2)
  int lr = b / 2, h = b % 2;
  const float* Wp = W + ((size_t)lr * 128 * 256) + (size_t)threadIdx.x * 256 + h * 128;
  const float* ap = av + (size_t)(lr * 2 + h) * 128;
  float acc = 0.f;
  for (int c = 0; c < 128; ++c) acc += Wp[c] * ap[c];
  wv[(size_t)(lr * 2 + h) * 128 + threadIdx.x] = acc;
}

// ---------------------------------------------------------------------------
// wt_prep: WT{h,l}[c][k] = split(W[k][c]).   (projection weights)
__global__ void wt_prep(const float* __restrict__ W, ushort_t* __restrict__ WTh,
                        ushort_t* __restrict__ WTl, int K, int C) {
  int k = blockIdx.x * 256 + threadIdx.x;
  int c = blockIdx.y;
  if (k >= K) return;
  ushort_t h, l;
  split_bf(W[(size_t)k * C + c], h, l);
  WTh[(size_t)c * K + k] = h;
  WTl[(size_t)c * K + k] = l;
}

// stk_prep: stacked src-weight for the G-GEMM. K-index kk = rel*256 + h*128 + j;
// ST{h,l}[c][kk] = split(Wrel[j][h*128+c]).  grid (2, 128), block 256.
__global__ void stk_prep(const float* __restrict__ Wa, const float* __restrict__ Wb,
                         ushort_t* __restrict__ STh, ushort_t* __restrict__ STl) {
  int rel = blockIdx.x;        // 0 -> Wa, 1 -> Wb
  int c = blockIdx.y;          // 0..127
  int t = threadIdx.x;         // h*128 + j
  const float* W = rel ? Wb : Wa;
  float v = W[(size_t)(t & 127) * 256 + (size_t)(t >> 7) * 128 + c];
  ushort_t hh, ll;
  split_bf(v, hh, ll);
  size_t idx = (size_t)c * 512 + (size_t)rel * 256 + t;
  STh[idx] = hh;
  STl[idx] = ll;
}

// combined per-dst-space biases: BS[0]=l0 pub+rep, BS[1]=l0 int+fol, BS[2]=l1 pub+rep
__global__ void bias_sum(const float* __restrict__ gbias, float* __restrict__ BS) {
  int c = threadIdx.x;  // 128
  BS[c]       = gbias[0 * 640 + 0 * 128 + c] + gbias[0 * 640 + 1 * 128 + c];
  BS[128 + c] = gbias[0 * 640 + 3 * 128 + c] + gbias[0 * 640 + 4 * 128 + c];
  BS[256 + c] = gbias[1 * 640 + 0 * 128 + c] + gbias[1 * 640 + 1 * 128 + c];
}

// ---------------------------------------------------------------------------
// Unified MFMA GEMM (bf16x2 split): Out[N][CF*16] = X[N][K] @ WT^T (+bias, relu).
template <int CF, bool BIAS, bool RELU>
__global__ __launch_bounds__(256) void gemm_mfma(const float* __restrict__ X,
                                                 const ushort_t* __restrict__ WTh,
                                                 const ushort_t* __restrict__ WTl,
                                                 const float* __restrict__ bv,
                                                 float* __restrict__ Out,
                                                 int N, int K) {
  __shared__ ushort_t Ah[64][32], Al[64][32];
  __shared__ ushort_t Bh[CF * 16][32], Bl[CF * 16][32];
  int t = threadIdx.x;
  int L = t & 63;
  int wv = t >> 6;
  int m = L & 15, quad = L >> 4;
  int row0 = blockIdx.x * 64;

  f4v acc[CF];
#pragma unroll
  for (int cf = 0; cf < CF; ++cf) acc[cf] = (f4v){0.f, 0.f, 0.f, 0.f};

  int nk = K >> 5;
  for (int kb = 0; kb < nk; ++kb) {
    int k0 = kb * 32;
#pragma unroll
    for (int i = 0; i < 2; ++i) {
      int s = t + 256 * i;
      int r = s >> 3, k4 = s & 7;
      int row = row0 + r;
      float4 v = make_float4(0.f, 0.f, 0.f, 0.f);
      if (row < N) v = *(const float4*)(X + (size_t)row * K + k0 + k4 * 4);
      ushort_t hx, lx, hy, ly, hz, lz, hw, lw;
      split_bf(v.x, hx, lx); split_bf(v.y, hy, ly);
      split_bf(v.z, hz, lz); split_bf(v.w, hw, lw);
      u4v h, l;
      h[0] = hx; h[1] = hy; h[2] = hz; h[3] = hw;
      l[0] = lx; l[1] = ly; l[2] = lz; l[3] = lw;
      *(u4v*)&Ah[r][k4 * 4] = h;
      *(u4v*)&Al[r][k4 * 4] = l;
    }
#pragma unroll
    for (int i = 0; i < CF / 4; ++i) {
      int s = t + 256 * i;
      int c = s >> 2, ch = s & 3;
      *(s8v*)&Bh[c][ch * 8] = *(const s8v*)(WTh + (size_t)c * K + k0 + ch * 8);
      *(s8v*)&Bl[c][ch * 8] = *(const s8v*)(WTl + (size_t)c * K + k0 + ch * 8);
    }
    __syncthreads();
    s8v a_h = *(const s8v*)&Ah[wv * 16 + m][quad * 8];
    s8v a_l = *(const s8v*)&Al[wv * 16 + m][quad * 8];
#pragma unroll
    for (int cf = 0; cf < CF; ++cf) {
      s8v b_h = *(const s8v*)&Bh[cf * 16 + m][quad * 8];
      s8v b_l = *(const s8v*)&Bl[cf * 16 + m][quad * 8];
      acc[cf] = __builtin_amdgcn_mfma_f32_16x16x32_bf16(a_h, b_h, acc[cf], 0, 0, 0);
      acc[cf] = __builtin_amdgcn_mfma_f32_16x16x32_bf16(a_h, b_l, acc[cf], 0, 0, 0);
      acc[cf] = __builtin_amdgcn_mfma_f32_16x16x32_bf16(a_l, b_h, acc[cf], 0, 0, 0);
    }
    __syncthreads();
  }

  float bvs[CF];
#pragma unroll
  for (int cf = 0; cf < CF; ++cf) bvs[cf] = BIAS ? bv[cf * 16 + m] : 0.f;
#pragma unroll
  for (int j = 0; j < 4; ++j) {
    int row = row0 + wv * 16 + quad * 4 + j;
    if (row < N) {
      float* o = Out + (size_t)row * (CF * 16) + m;
#pragma unroll
      for (int cf = 0; cf < CF; ++cf) {
        float vv = acc[cf][j] + bvs[cf];
        if (RELU) vv = fmaxf(vv, 0.f);
        o[cf * 16] = vv;
      }
    }
  }
}

// ---------------------------------------------------------------------------
// Consolidated CSR build over concatenated node space (4 relations).
// EOFF = {0,150k,450k,950k,1450k}; NOFF = {0,50k,100k,200k}.
__device__ __forceinline__ void rel_of(int g, int& r, int& loc, int& nb) {
  if (g < 450000) {
    if (g < 150000) { r = 0; loc = g;          nb = 0; }
    else            { r = 1; loc = g - 150000; nb = 50000; }
  } else if (g < 950000)  { r = 2; loc = g - 450000;  nb = 100000; }
  else                    { r = 3; loc = g - 950000;  nb = 200000; }
}
__global__ void histc_kernel(Ptrs4 dsts, int* __restrict__ cnt) {
  int g = blockIdx.x * 256 + threadIdx.x;
  if (g >= E_TOT) return;
  int r, loc, nb;
  rel_of(g, r, loc, nb);
  atomicAdd(&cnt[nb + dsts.p[r][loc]], 1);
}
__global__ __launch_bounds__(256) void scan1_kernel(const int* __restrict__ cnt,
                                                    int* __restrict__ excl,
                                                    int* __restrict__ partials, int Nd) {
  __shared__ int sb[256];
  int t = threadIdx.x;
  int base = blockIdx.x * 1024 + t * 4;
  int v[4];
#pragma unroll
  for (int j = 0; j < 4; ++j) v[j] = (base + j < Nd) ? cnt[base + j] : 0;
  int tot = v[0] + v[1] + v[2] + v[3];
  sb[t] = tot;
  __syncthreads();
  for (int off = 1; off < 256; off <<= 1) {
    int x = 0;
    if (t >= off) x = sb[t - off];
    __syncthreads();
    sb[t] += x;
    __syncthreads();
  }
  int ex = sb[t] - tot;
  if (t == 255) partials[blockIdx.x] = sb[t];
  int run = ex;
#pragma unroll
  for (int j = 0; j < 4; ++j) {
    if (base + j < Nd) excl[base + j] = run;
    run += v[j];
  }
}
__global__ __launch_bounds__(512) void scan2_kernel(int* __restrict__ partials, int B) {
  __shared__ int sb[512];
  int t = threadIdx.x;
  int v = (t < B) ? partials[t] : 0;
  sb[t] = v;
  __syncthreads();
  for (int off = 1; off < 512; off <<= 1) {
    int x = 0;
    if (t >= off) x = sb[t - off];
    __syncthreads();
    sb[t] += x;
    __syncthreads();
  }
  if (t < B) partials[t] = sb[t] - v;
}
__global__ void scan3_kernel(const int* __restrict__ excl, const int* __restrict__ partials,
                             int* __restrict__ rowptr, int* __restrict__ cursor) {
  int i = blockIdx.x * 256 + threadIdx.x;
  if (i < N_TOT) {
    int v = excl[i] + partials[i >> 10];
    rowptr[i] = v;
    cursor[i] = v;
  }
  if (i == 0) rowptr[N_TOT] = E_TOT;
}
__global__ void scatterc_kernel(Ptrs4 srcs, Ptrs4 dsts,
                                int* __restrict__ cursor, int* __restrict__ csrc) {
  int g = blockIdx.x * 256 + threadIdx.x;
  if (g >= E_TOT) return;
  int r, loc, nb;
  rel_of(g, r, loc, nb);
  int p = atomicAdd(&cursor[nb + dsts.p[r][loc]], 1);
  csrc[p] = srcs.p[r][loc];
}

// ---------------------------------------------------------------------------
// logits2: als_r[n][h] = H[n] . wsrcv_r[h]  for two relations at once.
__global__ __launch_bounds__(256) void logits2_kernel(const float* __restrict__ H,
                                                      const float* __restrict__ wsA,
                                                      const float* __restrict__ wsB,
                                                      float* __restrict__ alsA,
                                                      float* __restrict__ alsB, int Ns) {
  int n = blockIdx.x * 4 + (threadIdx.x >> 6);
  int lane = threadIdx.x & 63;
  if (n >= Ns) return;
  const float* hr = H + (size_t)n * 128;
  float ha = hr[lane], hb = hr[lane + 64];
  float p0 = ha * wsA[lane] + hb * wsA[lane + 64];
  float p1 = ha * wsA[128 + lane] + hb * wsA[192 + lane];
  float p2 = ha * wsB[lane] + hb * wsB[lane + 64];
  float p3 = ha * wsB[128 + lane] + hb * wsB[192 + lane];
#pragma unroll
  for (int mk = 32; mk; mk >>= 1) {
    p0 += __shfl_xor(p0, mk); p1 += __shfl_xor(p1, mk);
    p2 += __shfl_xor(p2, mk); p3 += __shfl_xor(p3, mk);
  }
  if (lane == 0) {
    *(float2*)(alsA + 2 * (size_t)n) = make_float2(p0, p1);
    *(float2*)(alsB + 2 * (size_t)n) = make_float2(p2, p3);
  }
}

// t-values (ald folded): dot of own Hd row with wdv, full-wave butterfly.
__device__ __forceinline__ void dst_tvals(const float* __restrict__ Hd, const float* __restrict__ wdv,
                                          int d, int lane, float& t0, float& t1) {
  const float* hr = Hd + (size_t)d * 128;
  float ha = hr[lane], hb = hr[lane + 64];
  t0 = ha * wdv[lane] + hb * wdv[lane + 64];
  t1 = ha * wdv[128 + lane] + hb * wdv[192 + lane];
#pragma unroll
  for (int mk = 32; mk; mk >>= 1) { t0 += __shfl_xor(t0, mk); t1 += __shfl_xor(t1, mk); }
}

// ---------------------------------------------------------------------------
// aggG_rel: per-dst alpha-weighted sum of raw H rows (both heads), 4 edges in
// flight per wave (half-wave h owns alternating edges; lane s holds ch 4s..4s+3).
// Writes 256 f32 [h0:128][h1:128] (scaled 0.5/den) to Grow.
__device__ __forceinline__ void aggG_rel(const int* __restrict__ rowptr,
                                         const int* __restrict__ csrc,
                                         const float* __restrict__ als,
                                         const float* __restrict__ Hs,
                                         float t0, float t1, int d, int h, int s,
                                         int lane, float* __restrict__ Grow) {
  int start = rowptr[d], end = rowptr[d + 1];
  float den0 = 0.f, den1 = 0.f;
  float a0[4] = {0.f, 0.f, 0.f, 0.f}, a1[4] = {0.f, 0.f, 0.f, 0.f};
  if (end > start) {
    int last = end - 1;
    for (int b0 = start; b0 < end; b0 += 4) {
      int eA = b0 + h, eB = b0 + 2 + h;
      bool vA = eA < end, vB = eB < end;
      eA = vA ? eA : last;
      eB = vB ? eB : last;
      int sA = csrc[eA], sB = csrc[eB];
      float2 alA = *(const float2*)(als + 2 * (size_t)sA);
      float2 alB = *(const float2*)(als + 2 * (size_t)sB);
      f4v xA = *(const f4v*)(Hs + (size_t)sA * 128 + 4 * s);
      f4v xB = *(const f4v*)(Hs + (size_t)sB * 128 + 4 * s);
      float wA0 = vA ? __expf(leaky(alA.x + t0)) : 0.f;
      float wA1 = vA ? __expf(leaky(alA.y + t1)) : 0.f;
      float wB0 = vB ? __expf(leaky(alB.x + t0)) : 0.f;
      float wB1 = vB ? __expf(leaky(alB.y + t1)) : 0.f;
      den0 += wA0 + wB0;
      den1 += wA1 + wB1;
#pragma unroll
      for (int j = 0; j < 4; ++j) {
        a0[j] += wA0 * xA[j] + wB0 * xB[j];
        a1[j] += wA1 * xA[j] + wB1 * xB[j];
      }
    }
  }
  den0 += __shfl_xor(den0, 32);
  den1 += __shfl_xor(den1, 32);
  float i0 = 0.5f / (den0 + 1e-16f);
  float i1 = 0.5f / (den1 + 1e-16f);
  f4v o0, o1;
#pragma unroll
  for (int j = 0; j < 4; ++j) {
    float u = a0[j] + __shfl_xor(a0[j], 32);
    float v = a1[j] + __shfl_xor(a1[j], 32);
    o0[j] = u * i0;
    o1[j] = v * i1;
  }
  if (lane < 32) {
    *(f4v*)(Grow + 4 * s) = o0;
    *(f4v*)(Grow + 128 + 4 * s) = o1;
  }
}

// aggG2: two relations sharing a dst space -> G[dl][512] = [relA h0,h1 | relB h0,h1]
__global__ __launch_bounds__(256) void aggG2_kernel(const int* __restrict__ rowA,
                                                    const int* __restrict__ rowB,
                                                    const int* __restrict__ csrc,
                                                    const float* __restrict__ alsA,
                                                    const float* __restrict__ alsB,
                                                    const float* __restrict__ wdvA,
                                                    const float* __restrict__ wdvB,
                                                    const float* __restrict__ Hs,
                                                    const float* __restrict__ Hd,
                                                    float* __restrict__ G,
                                                    int Nd, int dOff) {
  int dl = blockIdx.x * 4 + (threadIdx.x >> 6);
  int lane = threadIdx.x & 63;
  if (dl >= Nd) return;
  int d = dl + dOff;
  float tA0, tA1, tB0, tB1;
  dst_tvals(Hd, wdvA, d, lane, tA0, tA1);
  dst_tvals(Hd, wdvB, d, lane, tB0, tB1);
  int h = lane >> 5, s = lane & 31;
  float* Grow = G + (size_t)dl * 512;
  aggG_rel(rowA, csrc, alsA, Hs, tA0, tA1, d, h, s, lane, Grow);
  aggG_rel(rowB, csrc, alsB, Hs, tB0, tB1, d, h, s, lane, Grow + 256);
}

// ---------------------------------------------------------------------------
// classifier: out[n] = relu(H[n,:]@Wc1 + bc1) @ Wc2 + bc2.
__global__ __launch_bounds__(256) void classifier_kernel(const float* __restrict__ Hp,
                                                         const float* __restrict__ Wc1, const float* __restrict__ bc1,
                                                         const float* __restrict__ Wc2, const float* __restrict__ bc2,
                                                         float* __restrict__ out, int N) {
  __shared__ float sW[128 * 64];
  int t = threadIdx.x;
#pragma unroll
  for (int i = 0; i < 8; ++i) ((float4*)sW)[t + 256 * i] = ((const float4*)Wc1)[t + 256 * i];
  __syncthreads();
  int lane = t & 63, wv = t >> 6;
  float b = bc1[lane], w2 = Wc2[lane], b2 = bc2[0];
#pragma unroll
  for (int nn = 0; nn < 2; ++nn) {
    int n = blockIdx.x * 8 + wv * 2 + nn;
    if (n >= N) continue;
    const float* hr = Hp + (size_t)n * 128;
    float accz = b;
    for (int k = 0; k < 128; ++k) accz += hr[k] * sW[k * 64 + lane];
    float z = fmaxf(accz, 0.f) * w2;
#pragma unroll
    for (int off = 32; off; off >>= 1) z += __shfl_down(z, off);
    if (lane == 0) out[n] = z + b2;
  }
}

// ---------------------------------------------------------------------------
extern "C" void kernel_launch(void* const* d_in, const int* in_sizes, int n_in,
                              void* d_out, int out_size, void* d_ws, size_t ws_size,
                              hipStream_t stream) {
  const float* post_cls = (const float*)d_in[0];
  const float* user_x   = (const float*)d_in[1];
  const float* Wpost = (const float*)d_in[3];
  const float* bpost = (const float*)d_in[4];
  const float* Wuser = (const float*)d_in[5];
  const float* buser = (const float*)d_in[6];
  const float* gWsrc = (const float*)d_in[9];
  const float* gWdst = (const float*)d_in[10];
  const float* gasrc = (const float*)d_in[11];
  const float* gadst = (const float*)d_in[12];
  const float* gbias = (const float*)d_in[13];
  const float* Wc1 = (const float*)d_in[14];
  const float* bc1 = (const float*)d_in[15];
  const float* Wc2 = (const float*)d_in[16];
  const float* bc2 = (const float*)d_in[17];
  // relations kept: pub(18/19), rep(20/21), int(24/25), fol(26/27); con dropped (dead).
  Ptrs4 SRCS, DSTS;
  SRCS.p[0] = (const int*)d_in[18]; DSTS.p[0] = (const int*)d_in[19];
  SRCS.p[1] = (const int*)d_in[20]; DSTS.p[1] = (const int*)d_in[21];
  SRCS.p[2] = (const int*)d_in[24]; DSTS.p[2] = (const int*)d_in[25];
  SRCS.p[3] = (const int*)d_in[26]; DSTS.p[3] = (const int*)d_in[27];
  float* out = (float*)d_out;
  (void)ws_size; (void)in_sizes; (void)n_in; (void)out_size;

  // ---- workspace: floats, ints, ushorts (~218 MB)
  float* Wf = (float*)d_ws;
  size_t o = 0;
  float* WDSTV = Wf + o; o += 2560;
  float* WSRCV = Wf + o; o += 2560;
  float* BS    = Wf + o; o += 384;
  float* ALSa  = Wf + o; o += (size_t)N_USER * 2;
  float* ALSb  = Wf + o; o += (size_t)N_USER * 2;
  float* HU    = Wf + o; o += (size_t)N_USER * 128;
  float* HP    = Wf + o; o += (size_t)N_POST * 128;
  float* G     = Wf + o; o += (size_t)N_POST * 512;    // 50k x 512 f32, reused
  float* TMP   = Wf + o; o += (size_t)N_POST * 128;    // user chunk0 output
  int* Wi = (int*)(Wf + o);
  size_t io = 0;
  int* RP   = Wi + io; io += N_TOT + 1;
  int* CURS = Wi + io; io += N_TOT;
  int* CNT  = Wi + io; io += N_TOT;
  int* EXCL = Wi + io; io += N_TOT;
  int* PART = Wi + io; io += 512;
  int* CSRC = Wi + io; io += E_TOT;
  io = (io + 7) & ~(size_t)7;
  ushort_t* Wu = (ushort_t*)(Wi + io);
  size_t uo = 0;
  ushort_t* PWh = Wu + uo; uo += 128 * TEXT_D;
  ushort_t* PWl = Wu + uo; uo += 128 * TEXT_D;
  ushort_t* UWh = Wu + uo; uo += 128 * USER_D;
  ushort_t* UWl = Wu + uo; uo += 128 * USER_D;
  ushort_t* STh[3]; ushort_t* STl[3];
  for (int i = 0; i < 3; ++i) {
    STh[i] = Wu + uo; uo += 128 * 512;
    STl[i] = Wu + uo; uo += 128 * 512;
  }

  const int NOFF_PUB = 0, NOFF_REP = 50000, NOFF_INT = 100000, NOFF_FOL = 200000;

  // ---- consolidated CSR build (edges identical across layers)
  (void)hipMemsetAsync(CNT, 0, (size_t)N_TOT * sizeof(int), stream);
  histc_kernel<<<(E_TOT + 255) / 256, 256, 0, stream>>>(DSTS, CNT);
  int B = (N_TOT + 1023) / 1024;   // 293
  scan1_kernel<<<B, 256, 0, stream>>>(CNT, EXCL, PART, N_TOT);
  scan2_kernel<<<1, 512, 0, stream>>>(PART, B);
  scan3_kernel<<<(N_TOT + 255) / 256, 256, 0, stream>>>(EXCL, PART, RP, CURS);
  scatterc_kernel<<<(E_TOT + 255) / 256, 256, 0, stream>>>(SRCS, DSTS, CURS, CSRC);

  // ---- W preps
  wt_prep<<<dim3(3, 128), 256, 0, stream>>>(Wpost, PWh, PWl, TEXT_D, 128);
  wt_prep<<<dim3(1, 128), 256, 0, stream>>>(Wuser, UWh, UWl, USER_D, 128);
  // stacked src weights: [0]: l0 pub+rep, [1]: l0 int+fol, [2]: l1 pub+rep
  stk_prep<<<dim3(2, 128), 256, 0, stream>>>(gWsrc + (size_t)0 * 32768, gWsrc + (size_t)1 * 32768, STh[0], STl[0]);
  stk_prep<<<dim3(2, 128), 256, 0, stream>>>(gWsrc + (size_t)3 * 32768, gWsrc + (size_t)4 * 32768, STh[1], STl[1]);
  stk_prep<<<dim3(2, 128), 256, 0, stream>>>(gWsrc + (size_t)5 * 32768, gWsrc + (size_t)6 * 32768, STh[2], STl[2]);
  wvec_kernel<<<20, 128, 0, stream>>>(gWdst, gadst, WDSTV);
  wvec_kernel<<<20, 128, 0, stream>>>(gWsrc, gasrc, WSRCV);
  bias_sum<<<1, 128, 0, stream>>>(gbias, BS);

  // ---- projections (MFMA, bias fused, f32 out)
  gemm_mfma<8, true, false><<<(N_POST + 63) / 64, 256, 0, stream>>>(
      post_cls, PWh, PWl, bpost, HP, N_POST, TEXT_D);
  gemm_mfma<8, true, false><<<(N_USER + 63) / 64, 256, 0, stream>>>(
      user_x, UWh, UWl, buser, HU, N_USER, USER_D);

  // ---- layer 1: post  (pub + rep; src HU, dst HP in-place)
  logits2_kernel<<<(N_USER + 3) / 4, 256, 0, stream>>>(
      HU, WSRCV + 0 * 256, WSRCV + 1 * 256, ALSa, ALSb, N_USER);
  aggG2_kernel<<<(N_POST + 3) / 4, 256, 0, stream>>>(
      RP + NOFF_PUB, RP + NOFF_REP, CSRC, ALSa, ALSb,
      WDSTV + 0 * 256, WDSTV + 1 * 256, HU, HP, G, N_POST, 0);
  gemm_mfma<8, true, true><<<(N_POST + 63) / 64, 256, 0, stream>>>(
      G, STh[0], STl[0], BS + 0, HP, N_POST, 512);

  // ---- layer 1: user  (int + fol; src/dst HU, 2 chunks of 50k sharing G)
  logits2_kernel<<<(N_USER + 3) / 4, 256, 0, stream>>>(
      HU, WSRCV + 3 * 256, WSRCV + 4 * 256, ALSa, ALSb, N_USER);
  aggG2_kernel<<<(50000 + 3) / 4, 256, 0, stream>>>(
      RP + NOFF_INT, RP + NOFF_FOL, CSRC, ALSa, ALSb,
      WDSTV + 3 * 256, WDSTV + 4 * 256, HU, HU, G, 50000, 0);
  gemm_mfma<8, true, true><<<(50000 + 63) / 64, 256, 0, stream>>>(
      G, STh[1], STl[1], BS + 128, TMP, 50000, 512);
  aggG2_kernel<<<(50000 + 3) / 4, 256, 0, stream>>>(
      RP + NOFF_INT, RP + NOFF_FOL, CSRC, ALSa, ALSb,
      WDSTV + 3 * 256, WDSTV + 4 * 256, HU, HU, G, 50000, 50000);
  gemm_mfma<8, true, true><<<(50000 + 63) / 64, 256, 0, stream>>>(
      G, STh[1], STl[1], BS + 128, HU + (size_t)50000 * 128, 50000, 512);
  (void)hipMemcpyAsync(HU, TMP, (size_t)50000 * 128 * sizeof(float),
                       hipMemcpyDeviceToDevice, stream);

  // ---- layer 2: post only (output depends on nothing else)
  logits2_kernel<<<(N_USER + 3) / 4, 256, 0, stream>>>(
      HU, WSRCV + 5 * 256, WSRCV + 6 * 256, ALSa, ALSb, N_USER);
  aggG2_kernel<<<(N_POST + 3) / 4, 256, 0, stream>>>(
      RP + NOFF_PUB, RP + NOFF_REP, CSRC, ALSa, ALSb,
      WDSTV + 5 * 256, WDSTV + 6 * 256, HU, HP, G, N_POST, 0);
  gemm_mfma<8, true, true><<<(N_POST + 63) / 64, 256, 0, stream>>>(
      G, STh[2], STl[2], BS + 256, HP, N_POST, 512);

  classifier_kernel<<<(N_POST + 7) / 8, 256, 0, stream>>>(HP, Wc1, bc1, Wc2, bc2, out, N_POST);
}

// Round 2
// 1065.111 us; speedup vs baseline: 1.3393x; 1.0290x over previous
//
#include <hip/hip_runtime.h>
#include <cstdint>
#include <cstddef>

// FraudDetector hetero-GAT on MI355X.
// R10: (a) aggG2 restructured: one wave per (dst,rel), 8 edges in flight,
//      emits G pre-split as bf16 hi/lo (same rounding as old in-GEMM split).
//      (b) new gemm_split for the 4 G-GEMMs: copy-only staging (no split
//      VALU), BK=64, 2x2 wave grid (32x64 tiles/wave), XOR granule swizzle
//      (source+read side, LDS linear) -> <=2-way bank aliasing; next-tile
//      global loads issued before MFMA phase. (c) projection GEMM LDS padded
//      [32]->[40] to kill its 8-way ds_read conflicts.
#define N_USER 100000
#define N_POST 50000
#define TEXT_D 768
#define USER_D 64
#define E_TOT 1450000   // pub+rep+int+fol (entity path is dead code)
#define N_TOT 300000    // 50k+50k+100k+100k concatenated dst spaces

typedef unsigned short ushort_t;
typedef float f4v __attribute__((ext_vector_type(4)));
typedef short s8v __attribute__((ext_vector_type(8)));
typedef unsigned short u4v __attribute__((ext_vector_type(4)));
typedef unsigned short u8v __attribute__((ext_vector_type(8)));

__device__ __forceinline__ float leaky(float v) { return v > 0.f ? v : 0.2f * v; }
__device__ __forceinline__ void split_bf(float x, ushort_t& hi, ushort_t& lo) {
  unsigned u = __float_as_uint(x);
  hi = (ushort_t)(u >> 16);
  float r = x - __uint_as_float(u & 0xFFFF0000u);
  lo = (ushort_t)(__float_as_uint(r) >> 16);
}

struct Ptrs4 { const int* p[4]; };

// ---------------------------------------------------------------------------
// wvec: wv[(lr*2+h)*128+k] = sum_c W[lr][k][h*128+c] * a[lr][h][c]
__global__ void wvec_kernel(const float* __restrict__ W, const float* __restrict__ av,
                            float* __restrict__ wv) {
  int b = blockIdx.x;              // 20 = lr(10) * h(2)
  int lr = b / 2, h = b % 2;
  const float* Wp = W + ((size_t)lr * 128 * 256) + (size_t)threadIdx.x * 256 + h * 128;
  const float* ap = av + (size_t)(lr * 2 + h) * 128;
  float acc = 0.f;
  for (int c = 0; c < 128; ++c) acc += Wp[c] * ap[c];
  wv[(size_t)(lr * 2 + h) * 128 + threadIdx.x] = acc;
}

// ---------------------------------------------------------------------------
// wt_prep: WT{h,l}[c][k] = split(W[k][c]).   (projection weights)
__global__ void wt_prep(const float* __restrict__ W, ushort_t* __restrict__ WTh,
                        ushort_t* __restrict__ WTl, int K, int C) {
  int k = blockIdx.x * 256 + threadIdx.x;
  int c = blockIdx.y;
  if (k >= K) return;
  ushort_t h, l;
  split_bf(W[(size_t)k * C + c], h, l);
  WTh[(size_t)c * K + k] = h;
  WTl[(size_t)c * K + k] = l;
}

// stk_prep: stacked src-weight for the G-GEMM. kk = rel*256 + h*128 + j;
// ST{h,l}[c][kk] = split(Wrel[j][h*128+c]).  grid (2, 128), block 256.
__global__ void stk_prep(const float* __restrict__ Wa, const float* __restrict__ Wb,
                         ushort_t* __restrict__ STh, ushort_t* __restrict__ STl) {
  int rel = blockIdx.x;
  int c = blockIdx.y;
  int t = threadIdx.x;         // h*128 + j
  const float* W = rel ? Wb : Wa;
  float v = W[(size_t)(t & 127) * 256 + (size_t)(t >> 7) * 128 + c];
  ushort_t hh, ll;
  split_bf(v, hh, ll);
  size_t idx = (size_t)c * 512 + (size_t)rel * 256 + t;
  STh[idx] = hh;
  STl[idx] = ll;
}

// combined per-dst-space biases: BS[0]=l0 pub+rep, BS[1]=l0 int+fol, BS[2]=l1 pub+rep
__global__ void bias_sum(const float* __restrict__ gbias, float* __restrict__ BS) {
  int c = threadIdx.x;  // 128
  BS[c]       = gbias[0 * 640 + 0 * 128 + c] + gbias[0 * 640 + 1 * 128 + c];
  BS[128 + c] = gbias[0 * 640 + 3 * 128 + c] + gbias[0 * 640 + 4 * 128 + c];
  BS[256 + c] = gbias[1 * 640 + 0 * 128 + c] + gbias[1 * 640 + 1 * 128 + c];
}

// ---------------------------------------------------------------------------
// Projection GEMM (f32 input, bf16x2 split in-kernel): Out = X@WT^T + bias.
// LDS rows padded to 40 ushorts (80B stride, 16B aligned) -> <=2-way conflicts.
template <int CF, bool BIAS>
__global__ __launch_bounds__(256) void gemm_mfma(const float* __restrict__ X,
                                                 const ushort_t* __restrict__ WTh,
                                                 const ushort_t* __restrict__ WTl,
                                                 const float* __restrict__ bv,
                                                 float* __restrict__ Out,
                                                 int N, int K) {
  __shared__ ushort_t Ah[64][40], Al[64][40];
  __shared__ ushort_t Bh[CF * 16][40], Bl[CF * 16][40];
  int t = threadIdx.x;
  int L = t & 63;
  int wv = t >> 6;
  int m = L & 15, quad = L >> 4;
  int row0 = blockIdx.x * 64;

  f4v acc[CF];
#pragma unroll
  for (int cf = 0; cf < CF; ++cf) acc[cf] = (f4v){0.f, 0.f, 0.f, 0.f};

  int nk = K >> 5;
  for (int kb = 0; kb < nk; ++kb) {
    int k0 = kb * 32;
#pragma unroll
    for (int i = 0; i < 2; ++i) {
      int s = t + 256 * i;
      int r = s >> 3, k4 = s & 7;
      int row = row0 + r;
      float4 v = make_float4(0.f, 0.f, 0.f, 0.f);
      if (row < N) v = *(const float4*)(X + (size_t)row * K + k0 + k4 * 4);
      ushort_t hx, lx, hy, ly, hz, lz, hw, lw;
      split_bf(v.x, hx, lx); split_bf(v.y, hy, ly);
      split_bf(v.z, hz, lz); split_bf(v.w, hw, lw);
      u4v h, l;
      h[0] = hx; h[1] = hy; h[2] = hz; h[3] = hw;
      l[0] = lx; l[1] = ly; l[2] = lz; l[3] = lw;
      *(u4v*)&Ah[r][k4 * 4] = h;
      *(u4v*)&Al[r][k4 * 4] = l;
    }
#pragma unroll
    for (int i = 0; i < CF / 4; ++i) {
      int s = t + 256 * i;
      int c = s >> 2, ch = s & 3;
      *(u8v*)&Bh[c][ch * 8] = *(const u8v*)(WTh + (size_t)c * K + k0 + ch * 8);
      *(u8v*)&Bl[c][ch * 8] = *(const u8v*)(WTl + (size_t)c * K + k0 + ch * 8);
    }
    __syncthreads();
    s8v a_h = *(const s8v*)&Ah[wv * 16 + m][quad * 8];
    s8v a_l = *(const s8v*)&Al[wv * 16 + m][quad * 8];
#pragma unroll
    for (int cf = 0; cf < CF; ++cf) {
      s8v b_h = *(const s8v*)&Bh[cf * 16 + m][quad * 8];
      s8v b_l = *(const s8v*)&Bl[cf * 16 + m][quad * 8];
      acc[cf] = __builtin_amdgcn_mfma_f32_16x16x32_bf16(a_h, b_h, acc[cf], 0, 0, 0);
      acc[cf] = __builtin_amdgcn_mfma_f32_16x16x32_bf16(a_h, b_l, acc[cf], 0, 0, 0);
      acc[cf] = __builtin_amdgcn_mfma_f32_16x16x32_bf16(a_l, b_h, acc[cf], 0, 0, 0);
    }
    __syncthreads();
  }

  float bvs[CF];
#pragma unroll
  for (int cf = 0; cf < CF; ++cf) bvs[cf] = BIAS ? bv[cf * 16 + m] : 0.f;
#pragma unroll
  for (int j = 0; j < 4; ++j) {
    int row = row0 + wv * 16 + quad * 4 + j;
    if (row < N) {
      float* o = Out + (size_t)row * (CF * 16) + m;
#pragma unroll
      for (int cf = 0; cf < CF; ++cf) o[cf * 16] = acc[cf][j] + bvs[cf];
    }
  }
}

// ---------------------------------------------------------------------------
// gemm_split: Out[N][128] = relu( (Ah+Al)[N][K] @ (Bh+Bl)[128][K]^T + bias ).
// Inputs pre-split bf16.  Tile 64x128, 4 waves 2x2 (32x64 each), BK=64.
// LDS physically linear granules; XOR swizzle (q ^= row&7) applied on the
// global SOURCE address at staging and on the LDS READ -> <=2-way aliasing.
template <int NK>   // K = NK*64
__global__ __launch_bounds__(256) void gemm_split(const ushort_t* __restrict__ Agh,
                                                  const ushort_t* __restrict__ Agl,
                                                  const ushort_t* __restrict__ Bgh,
                                                  const ushort_t* __restrict__ Bgl,
                                                  const float* __restrict__ bv,
                                                  float* __restrict__ Out, int N) {
  constexpr int K = NK * 64;
  __shared__ __align__(16) ushort_t LAh[64 * 64], LAl[64 * 64];
  __shared__ __align__(16) ushort_t LBh[128 * 64], LBl[128 * 64];
  int t = threadIdx.x;
  int lane = t & 63, w = t >> 6;
  int m = lane & 15, quad = lane >> 4;
  int wr = w >> 1, wc = w & 1;
  int row0 = blockIdx.x * 64;

  // staging source coords (swizzled): granule p -> (r, q=(p&7)^(r&7))
  int arow[2], acol[2];
#pragma unroll
  for (int i = 0; i < 2; ++i) {
    int p = t + 256 * i;
    int r = p >> 3, q = (p & 7) ^ (r & 7);
    int row = row0 + r;
    if (row >= N) row = N - 1;
    arow[i] = row; acol[i] = q * 8;
  }
  int bcol[4], bq[4];
#pragma unroll
  for (int i = 0; i < 4; ++i) {
    int p = t + 256 * i;
    int c = p >> 3, q = (p & 7) ^ (c & 7);
    bcol[i] = c; bq[i] = q * 8;
  }

  f4v acc[2][4];
#pragma unroll
  for (int mt = 0; mt < 2; ++mt)
#pragma unroll
    for (int ct = 0; ct < 4; ++ct) acc[mt][ct] = (f4v){0.f, 0.f, 0.f, 0.f};

  u8v rah[2], ral[2], rbh[4], rbl[4];
  auto LOAD = [&](int kb) {
    int k0 = kb * 64;
#pragma unroll
    for (int i = 0; i < 2; ++i) {
      rah[i] = *(const u8v*)(Agh + (size_t)arow[i] * K + k0 + acol[i]);
      ral[i] = *(const u8v*)(Agl + (size_t)arow[i] * K + k0 + acol[i]);
    }
#pragma unroll
    for (int i = 0; i < 4; ++i) {
      rbh[i] = *(const u8v*)(Bgh + (size_t)bcol[i] * K + k0 + bq[i]);
      rbl[i] = *(const u8v*)(Bgl + (size_t)bcol[i] * K + k0 + bq[i]);
    }
  };
  LOAD(0);
  for (int kb = 0; kb < NK; ++kb) {
    __syncthreads();    // previous iteration's reads done before overwrite
#pragma unroll
    for (int i = 0; i < 2; ++i) {
      *(u8v*)&LAh[(size_t)(t + 256 * i) * 8] = rah[i];
      *(u8v*)&LAl[(size_t)(t + 256 * i) * 8] = ral[i];
    }
#pragma unroll
    for (int i = 0; i < 4; ++i) {
      *(u8v*)&LBh[(size_t)(t + 256 * i) * 8] = rbh[i];
      *(u8v*)&LBl[(size_t)(t + 256 * i) * 8] = rbl[i];
    }
    __syncthreads();
    if (kb + 1 < NK) LOAD(kb + 1);   // issue-early; hidden under MFMA phase
#pragma unroll
    for (int ks = 0; ks < 2; ++ks) {
      s8v ah[2], alo[2], bh[4], blo[4];
#pragma unroll
      for (int mt = 0; mt < 2; ++mt) {
        int r = wr * 32 + mt * 16 + m;
        int gr = r * 8 + ((ks * 4 + quad) ^ (m & 7));
        ah[mt] = *(const s8v*)&LAh[(size_t)gr * 8];
        alo[mt] = *(const s8v*)&LAl[(size_t)gr * 8];
      }
#pragma unroll
      for (int ct = 0; ct < 4; ++ct) {
        int c = wc * 64 + ct * 16 + m;
        int gc = c * 8 + ((ks * 4 + quad) ^ (m & 7));
        bh[ct] = *(const s8v*)&LBh[(size_t)gc * 8];
        blo[ct] = *(const s8v*)&LBl[(size_t)gc * 8];
      }
#pragma unroll
      for (int mt = 0; mt < 2; ++mt)
#pragma unroll
        for (int ct = 0; ct < 4; ++ct) {
          acc[mt][ct] = __builtin_amdgcn_mfma_f32_16x16x32_bf16(ah[mt], bh[ct], acc[mt][ct], 0, 0, 0);
          acc[mt][ct] = __builtin_amdgcn_mfma_f32_16x16x32_bf16(ah[mt], blo[ct], acc[mt][ct], 0, 0, 0);
          acc[mt][ct] = __builtin_amdgcn_mfma_f32_16x16x32_bf16(alo[mt], bh[ct], acc[mt][ct], 0, 0, 0);
        }
    }
  }
  float bb[4];
#pragma unroll
  for (int ct = 0; ct < 4; ++ct) bb[ct] = bv[wc * 64 + ct * 16 + m];
#pragma unroll
  for (int mt = 0; mt < 2; ++mt)
#pragma unroll
    for (int j = 0; j < 4; ++j) {
      int row = row0 + wr * 32 + mt * 16 + quad * 4 + j;
      if (row < N) {
        float* o = Out + (size_t)row * 128 + wc * 64 + m;
#pragma unroll
        for (int ct = 0; ct < 4; ++ct) o[ct * 16] = fmaxf(acc[mt][ct][j] + bb[ct], 0.f);
      }
    }
}

// ---------------------------------------------------------------------------
// Consolidated CSR build over concatenated node space (4 relations).
__device__ __forceinline__ void rel_of(int g, int& r, int& loc, int& nb) {
  if (g < 450000) {
    if (g < 150000) { r = 0; loc = g;          nb = 0; }
    else            { r = 1; loc = g - 150000; nb = 50000; }
  } else if (g < 950000)  { r = 2; loc = g - 450000;  nb = 100000; }
  else                    { r = 3; loc = g - 950000;  nb = 200000; }
}
__global__ void histc_kernel(Ptrs4 dsts, int* __restrict__ cnt) {
  int g = blockIdx.x * 256 + threadIdx.x;
  if (g >= E_TOT) return;
  int r, loc, nb;
  rel_of(g, r, loc, nb);
  atomicAdd(&cnt[nb + dsts.p[r][loc]], 1);
}
__global__ __launch_bounds__(256) void scan1_kernel(const int* __restrict__ cnt,
                                                    int* __restrict__ excl,
                                                    int* __restrict__ partials, int Nd) {
  __shared__ int sb[256];
  int t = threadIdx.x;
  int base = blockIdx.x * 1024 + t * 4;
  int v[4];
#pragma unroll
  for (int j = 0; j < 4; ++j) v[j] = (base + j < Nd) ? cnt[base + j] : 0;
  int tot = v[0] + v[1] + v[2] + v[3];
  sb[t] = tot;
  __syncthreads();
  for (int off = 1; off < 256; off <<= 1) {
    int x = 0;
    if (t >= off) x = sb[t - off];
    __syncthreads();
    sb[t] += x;
    __syncthreads();
  }
  int ex = sb[t] - tot;
  if (t == 255) partials[blockIdx.x] = sb[t];
  int run = ex;
#pragma unroll
  for (int j = 0; j < 4; ++j) {
    if (base + j < Nd) excl[base + j] = run;
    run += v[j];
  }
}
__global__ __launch_bounds__(512) void scan2_kernel(int* __restrict__ partials, int B) {
  __shared__ int sb[512];
  int t = threadIdx.x;
  int v = (t < B) ? partials[t] : 0;
  sb[t] = v;
  __syncthreads();
  for (int off = 1; off < 512; off <<= 1) {
    int x = 0;
    if (t >= off) x = sb[t - off];
    __syncthreads();
    sb[t] += x;
    __syncthreads();
  }
  if (t < B) partials[t] = sb[t] - v;
}
__global__ void scan3_kernel(const int* __restrict__ excl, const int* __restrict__ partials,
                             int* __restrict__ rowptr, int* __restrict__ cursor) {
  int i = blockIdx.x * 256 + threadIdx.x;
  if (i < N_TOT) {
    int v = excl[i] + partials[i >> 10];
    rowptr[i] = v;
    cursor[i] = v;
  }
  if (i == 0) rowptr[N_TOT] = E_TOT;
}
__global__ void scatterc_kernel(Ptrs4 srcs, Ptrs4 dsts,
                                int* __restrict__ cursor, int* __restrict__ csrc) {
  int g = blockIdx.x * 256 + threadIdx.x;
  if (g >= E_TOT) return;
  int r, loc, nb;
  rel_of(g, r, loc, nb);
  int p = atomicAdd(&cursor[nb + dsts.p[r][loc]], 1);
  csrc[p] = srcs.p[r][loc];
}

// ---------------------------------------------------------------------------
// logits2: als_r[n][h] = H[n] . wsrcv_r[h]  for two relations at once.
__global__ __launch_bounds__(256) void logits2_kernel(const float* __restrict__ H,
                                                      const float* __restrict__ wsA,
                                                      const float* __restrict__ wsB,
                                                      float* __restrict__ alsA,
                                                      float* __restrict__ alsB, int Ns) {
  int n = blockIdx.x * 4 + (threadIdx.x >> 6);
  int lane = threadIdx.x & 63;
  if (n >= Ns) return;
  const float* hr = H + (size_t)n * 128;
  float ha = hr[lane], hb = hr[lane + 64];
  float p0 = ha * wsA[lane] + hb * wsA[lane + 64];
  float p1 = ha * wsA[128 + lane] + hb * wsA[192 + lane];
  float p2 = ha * wsB[lane] + hb * wsB[lane + 64];
  float p3 = ha * wsB[128 + lane] + hb * wsB[192 + lane];
#pragma unroll
  for (int mk = 32; mk; mk >>= 1) {
    p0 += __shfl_xor(p0, mk); p1 += __shfl_xor(p1, mk);
    p2 += __shfl_xor(p2, mk); p3 += __shfl_xor(p3, mk);
  }
  if (lane == 0) {
    *(float2*)(alsA + 2 * (size_t)n) = make_float2(p0, p1);
    *(float2*)(alsB + 2 * (size_t)n) = make_float2(p2, p3);
  }
}

// t-values (ald folded): dot of own Hd row with wdv, full-wave butterfly.
__device__ __forceinline__ void dst_tvals(const float* __restrict__ Hd, const float* __restrict__ wdv,
                                          int d, int lane, float& t0, float& t1) {
  const float* hr = Hd + (size_t)d * 128;
  float ha = hr[lane], hb = hr[lane + 64];
  t0 = ha * wdv[lane] + hb * wdv[lane + 64];
  t1 = ha * wdv[128 + lane] + hb * wdv[192 + lane];
#pragma unroll
  for (int mk = 32; mk; mk >>= 1) { t0 += __shfl_xor(t0, mk); t1 += __shfl_xor(t1, mk); }
}

// ---------------------------------------------------------------------------
// aggG_rel: per-(dst,rel) alpha-weighted sum of raw H rows (both heads),
// 8 edges in flight per wave (4 per half-wave).  Output split-bf16.
__device__ __forceinline__ void aggG_rel(const int* __restrict__ rowptr,
                                         const int* __restrict__ csrc,
                                         const float* __restrict__ als,
                                         const float* __restrict__ Hs,
                                         float t0, float t1, int d, int h, int s,
                                         int lane, ushort_t* __restrict__ GrowH,
                                         ushort_t* __restrict__ GrowL) {
  int start = rowptr[d], end = rowptr[d + 1];
  float den0 = 0.f, den1 = 0.f;
  float a0[4] = {0.f, 0.f, 0.f, 0.f}, a1[4] = {0.f, 0.f, 0.f, 0.f};
  if (end > start) {
    int last = end - 1;
    for (int b0 = start; b0 < end; b0 += 8) {
      int e[4]; bool vl[4]; int sid[4];
#pragma unroll
      for (int j = 0; j < 4; ++j) {
        int ee = b0 + 2 * j + h;
        vl[j] = ee < end;
        e[j] = vl[j] ? ee : last;
      }
#pragma unroll
      for (int j = 0; j < 4; ++j) sid[j] = csrc[e[j]];
      float2 al[4]; f4v x[4];
#pragma unroll
      for (int j = 0; j < 4; ++j) {
        al[j] = *(const float2*)(als + 2 * (size_t)sid[j]);
        x[j] = *(const f4v*)(Hs + (size_t)sid[j] * 128 + 4 * s);
      }
#pragma unroll
      for (int j = 0; j < 4; ++j) {
        float w0 = vl[j] ? __expf(leaky(al[j].x + t0)) : 0.f;
        float w1 = vl[j] ? __expf(leaky(al[j].y + t1)) : 0.f;
        den0 += w0; den1 += w1;
#pragma unroll
        for (int q = 0; q < 4; ++q) {
          a0[q] += w0 * x[j][q];
          a1[q] += w1 * x[j][q];
        }
      }
    }
  }
  den0 += __shfl_xor(den0, 32);
  den1 += __shfl_xor(den1, 32);
  float i0 = 0.5f / (den0 + 1e-16f);
  float i1 = 0.5f / (den1 + 1e-16f);
  f4v o0, o1;
#pragma unroll
  for (int q = 0; q < 4; ++q) {
    float u = a0[q] + __shfl_xor(a0[q], 32);
    float v = a1[q] + __shfl_xor(a1[q], 32);
    o0[q] = u * i0;
    o1[q] = v * i1;
  }
  if (lane < 32) {
    u4v g0h, g0l, g1h, g1l;
#pragma unroll
    for (int q = 0; q < 4; ++q) {
      ushort_t hh, ll;
      split_bf(o0[q], hh, ll); g0h[q] = hh; g0l[q] = ll;
      split_bf(o1[q], hh, ll); g1h[q] = hh; g1l[q] = ll;
    }
    *(u4v*)(GrowH + 4 * s) = g0h;
    *(u4v*)(GrowL + 4 * s) = g0l;
    *(u4v*)(GrowH + 128 + 4 * s) = g1h;
    *(u4v*)(GrowL + 128 + 4 * s) = g1l;
  }
}

// aggG2: block = 4 waves = 2 dsts x 2 rels. G row [relA h0|h1 | relB h0|h1].
__global__ __launch_bounds__(256) void aggG2_kernel(const int* __restrict__ rowA,
                                                    const int* __restrict__ rowB,
                                                    const int* __restrict__ csrc,
                                                    const float* __restrict__ alsA,
                                                    const float* __restrict__ alsB,
                                                    const float* __restrict__ wdvA,
                                                    const float* __restrict__ wdvB,
                                                    const float* __restrict__ Hs,
                                                    const float* __restrict__ Hd,
                                                    ushort_t* __restrict__ Gh,
                                                    ushort_t* __restrict__ Gl,
                                                    int Nd, int dOff) {
  int w = threadIdx.x >> 6;
  int lane = threadIdx.x & 63;
  int dl = blockIdx.x * 2 + (w >> 1);
  int rel = w & 1;
  if (dl >= Nd) return;
  int d = dl + dOff;
  const int* rp = rel ? rowB : rowA;
  const float* alsP = rel ? alsB : alsA;
  const float* wdv = rel ? wdvB : wdvA;
  float t0, t1;
  dst_tvals(Hd, wdv, d, lane, t0, t1);
  int h = lane >> 5, s = lane & 31;
  aggG_rel(rp, csrc, alsP, Hs, t0, t1, d, h, s, lane,
           Gh + (size_t)dl * 512 + rel * 256, Gl + (size_t)dl * 512 + rel * 256);
}

// ---------------------------------------------------------------------------
// classifier: out[n] = relu(H[n,:]@Wc1 + bc1) @ Wc2 + bc2.
__global__ __launch_bounds__(256) void classifier_kernel(const float* __restrict__ Hp,
                                                         const float* __restrict__ Wc1, const float* __restrict__ bc1,
                                                         const float* __restrict__ Wc2, const float* __restrict__ bc2,
                                                         float* __restrict__ out, int N) {
  __shared__ float sW[128 * 64];
  int t = threadIdx.x;
#pragma unroll
  for (int i = 0; i < 8; ++i) ((float4*)sW)[t + 256 * i] = ((const float4*)Wc1)[t + 256 * i];
  __syncthreads();
  int lane = t & 63, wv = t >> 6;
  float b = bc1[lane], w2 = Wc2[lane], b2 = bc2[0];
#pragma unroll
  for (int nn = 0; nn < 2; ++nn) {
    int n = blockIdx.x * 8 + wv * 2 + nn;
    if (n >= N) continue;
    const float* hr = Hp + (size_t)n * 128;
    float accz = b;
    for (int k = 0; k < 128; ++k) accz += hr[k] * sW[k * 64 + lane];
    float z = fmaxf(accz, 0.f) * w2;
#pragma unroll
    for (int off = 32; off; off >>= 1) z += __shfl_down(z, off);
    if (lane == 0) out[n] = z + b2;
  }
}

// ---------------------------------------------------------------------------
extern "C" void kernel_launch(void* const* d_in, const int* in_sizes, int n_in,
                              void* d_out, int out_size, void* d_ws, size_t ws_size,
                              hipStream_t stream) {
  const float* post_cls = (const float*)d_in[0];
  const float* user_x   = (const float*)d_in[1];
  const float* Wpost = (const float*)d_in[3];
  const float* bpost = (const float*)d_in[4];
  const float* Wuser = (const float*)d_in[5];
  const float* buser = (const float*)d_in[6];
  const float* gWsrc = (const float*)d_in[9];
  const float* gWdst = (const float*)d_in[10];
  const float* gasrc = (const float*)d_in[11];
  const float* gadst = (const float*)d_in[12];
  const float* gbias = (const float*)d_in[13];
  const float* Wc1 = (const float*)d_in[14];
  const float* bc1 = (const float*)d_in[15];
  const float* Wc2 = (const float*)d_in[16];
  const float* bc2 = (const float*)d_in[17];
  // relations kept: pub(18/19), rep(20/21), int(24/25), fol(26/27); con dropped (dead).
  Ptrs4 SRCS, DSTS;
  SRCS.p[0] = (const int*)d_in[18]; DSTS.p[0] = (const int*)d_in[19];
  SRCS.p[1] = (const int*)d_in[20]; DSTS.p[1] = (const int*)d_in[21];
  SRCS.p[2] = (const int*)d_in[24]; DSTS.p[2] = (const int*)d_in[25];
  SRCS.p[3] = (const int*)d_in[26]; DSTS.p[3] = (const int*)d_in[27];
  float* out = (float*)d_out;
  (void)ws_size; (void)in_sizes; (void)n_in; (void)out_size;

  // ---- workspace: floats, ints, ushorts (~218 MB)
  float* Wf = (float*)d_ws;
  size_t o = 0;
  float* WDSTV = Wf + o; o += 2560;
  float* WSRCV = Wf + o; o += 2560;
  float* BS    = Wf + o; o += 384;
  float* ALSa  = Wf + o; o += (size_t)N_USER * 2;
  float* ALSb  = Wf + o; o += (size_t)N_USER * 2;
  float* HU    = Wf + o; o += (size_t)N_USER * 128;
  float* HP    = Wf + o; o += (size_t)N_POST * 128;
  float* TMP   = Wf + o; o += (size_t)N_POST * 128;    // user chunk0 output
  int* Wi = (int*)(Wf + o);
  size_t io = 0;
  int* RP   = Wi + io; io += N_TOT + 1;
  int* CURS = Wi + io; io += N_TOT;
  int* CNT  = Wi + io; io += N_TOT;
  int* EXCL = Wi + io; io += N_TOT;
  int* PART = Wi + io; io += 512;
  int* CSRC = Wi + io; io += E_TOT;
  io = (io + 7) & ~(size_t)7;
  ushort_t* Wu = (ushort_t*)(Wi + io);
  size_t uo = 0;
  ushort_t* PWh = Wu + uo; uo += 128 * TEXT_D;
  ushort_t* PWl = Wu + uo; uo += 128 * TEXT_D;
  ushort_t* UWh = Wu + uo; uo += 128 * USER_D;
  ushort_t* UWl = Wu + uo; uo += 128 * USER_D;
  ushort_t* STh[3]; ushort_t* STl[3];
  for (int i = 0; i < 3; ++i) {
    STh[i] = Wu + uo; uo += 128 * 512;
    STl[i] = Wu + uo; uo += 128 * 512;
  }
  ushort_t* Gh = Wu + uo; uo += (size_t)N_POST * 512;   // 50k x 512 bf16-hi
  ushort_t* Gl = Wu + uo; uo += (size_t)N_POST * 512;   // 50k x 512 bf16-lo

  const int NOFF_PUB = 0, NOFF_REP = 50000, NOFF_INT = 100000, NOFF_FOL = 200000;

  // ---- consolidated CSR build (edges identical across layers)
  (void)hipMemsetAsync(CNT, 0, (size_t)N_TOT * sizeof(int), stream);
  histc_kernel<<<(E_TOT + 255) / 256, 256, 0, stream>>>(DSTS, CNT);
  int B = (N_TOT + 1023) / 1024;   // 293
  scan1_kernel<<<B, 256, 0, stream>>>(CNT, EXCL, PART, N_TOT);
  scan2_kernel<<<1, 512, 0, stream>>>(PART, B);
  scan3_kernel<<<(N_TOT + 255) / 256, 256, 0, stream>>>(EXCL, PART, RP, CURS);
  scatterc_kernel<<<(E_TOT + 255) / 256, 256, 0, stream>>>(SRCS, DSTS, CURS, CSRC);

  // ---- W preps
  wt_prep<<<dim3(3, 128), 256, 0, stream>>>(Wpost, PWh, PWl, TEXT_D, 128);
  wt_prep<<<dim3(1, 128), 256, 0, stream>>>(Wuser, UWh, UWl, USER_D, 128);
  // stacked src weights: [0]: l0 pub+rep, [1]: l0 int+fol, [2]: l1 pub+rep
  stk_prep<<<dim3(2, 128), 256, 0, stream>>>(gWsrc + (size_t)0 * 32768, gWsrc + (size_t)1 * 32768, STh[0], STl[0]);
  stk_prep<<<dim3(2, 128), 256, 0, stream>>>(gWsrc + (size_t)3 * 32768, gWsrc + (size_t)4 * 32768, STh[1], STl[1]);
  stk_prep<<<dim3(2, 128), 256, 0, stream>>>(gWsrc + (size_t)5 * 32768, gWsrc + (size_t)6 * 32768, STh[2], STl[2]);
  wvec_kernel<<<20, 128, 0, stream>>>(gWdst, gadst, WDSTV);
  wvec_kernel<<<20, 128, 0, stream>>>(gWsrc, gasrc, WSRCV);
  bias_sum<<<1, 128, 0, stream>>>(gbias, BS);

  // ---- projections (MFMA, bias fused, f32 out)
  gemm_mfma<8, true><<<(N_POST + 63) / 64, 256, 0, stream>>>(
      post_cls, PWh, PWl, bpost, HP, N_POST, TEXT_D);
  gemm_mfma<8, true><<<(N_USER + 63) / 64, 256, 0, stream>>>(
      user_x, UWh, UWl, buser, HU, N_USER, USER_D);

  // ---- layer 1: post  (pub + rep; src HU, dst HP in-place)
  logits2_kernel<<<(N_USER + 3) / 4, 256, 0, stream>>>(
      HU, WSRCV + 0 * 256, WSRCV + 1 * 256, ALSa, ALSb, N_USER);
  aggG2_kernel<<<(N_POST + 1) / 2, 256, 0, stream>>>(
      RP + NOFF_PUB, RP + NOFF_REP, CSRC, ALSa, ALSb,
      WDSTV + 0 * 256, WDSTV + 1 * 256, HU, HP, Gh, Gl, N_POST, 0);
  gemm_split<8><<<(N_POST + 63) / 64, 256, 0, stream>>>(
      Gh, Gl, STh[0], STl[0], BS + 0, HP, N_POST);

  // ---- layer 1: user  (int + fol; src/dst HU, 2 chunks of 50k sharing G)
  logits2_kernel<<<(N_USER + 3) / 4, 256, 0, stream>>>(
      HU, WSRCV + 3 * 256, WSRCV + 4 * 256, ALSa, ALSb, N_USER);
  aggG2_kernel<<<(50000 + 1) / 2, 256, 0, stream>>>(
      RP + NOFF_INT, RP + NOFF_FOL, CSRC, ALSa, ALSb,
      WDSTV + 3 * 256, WDSTV + 4 * 256, HU, HU, Gh, Gl, 50000, 0);
  gemm_split<8><<<(50000 + 63) / 64, 256, 0, stream>>>(
      Gh, Gl, STh[1], STl[1], BS + 128, TMP, 50000);
  aggG2_kernel<<<(50000 + 1) / 2, 256, 0, stream>>>(
      RP + NOFF_INT, RP + NOFF_FOL, CSRC, ALSa, ALSb,
      WDSTV + 3 * 256, WDSTV + 4 * 256, HU, HU, Gh, Gl, 50000, 50000);
  gemm_split<8><<<(50000 + 63) / 64, 256, 0, stream>>>(
      Gh, Gl, STh[1], STl[1], BS + 128, HU + (size_t)50000 * 128, 50000);
  (void)hipMemcpyAsync(HU, TMP, (size_t)50000 * 128 * sizeof(float),
                       hipMemcpyDeviceToDevice, stream);

  // ---- layer 2: post only (output depends on nothing else)
  logits2_kernel<<<(N_USER + 3) / 4, 256, 0, stream>>>(
      HU, WSRCV + 5 * 256, WSRCV + 6 * 256, ALSa, ALSb, N_USER);
  aggG2_kernel<<<(N_POST + 1) / 2, 256, 0, stream>>>(
      RP + NOFF_PUB, RP + NOFF_REP, CSRC, ALSa, ALSb,
      WDSTV + 5 * 256, WDSTV + 6 * 256, HU, HP, Gh, Gl, N_POST, 0);
  gemm_split<8><<<(N_POST + 63) / 64, 256, 0, stream>>>(
      Gh, Gl, STh[2], STl[2], BS + 256, HP, N_POST);

  classifier_kernel<<<(N_POST + 7) / 8, 256, 0, stream>>>(HP, Wc1, bc1, Wc2, bc2, out, N_POST);
}